// Round 6
// baseline (149.432 us; speedup 1.0000x reference)
//
#include <hip/hip_runtime.h>

// out[b,h] = sum_{i,j} cb[h, i*64+j] * in1[b,i] * in2[b,j]
// B = 4096, dim1 = dim2 = 64, H = 4096.
//
// Round-5 structure:
//   prep_kernel: table[h][0..63] = compacted cb row (d_ws), plus
//                meta[h] = i1 | i2<<8 | l1l2<<16.
//   tp_kernel: 512 thr (8 waves), 64b x 64h tile, so-quarter flushes.
//     - cb operands: read via wave-uniform pointer with compile-time
//       offsets -> backend emits s_load_dwordx16 into SGPRs; fma uses the
//       SGPR directly (1 SGPR src allowed per VALU op). Kills the
//       one-readlane-per-MAC overhead of rounds 2-4 (~28 VALU/row).
//     - LDS x-tiles [batch][dim] stride 65 -> lane-adjacent ds_read2_b32.
//     - meta prefetched one phase ahead (scalar pipe).

#define SDIM 65   // s1/s2 row stride: bank = (t + d) % 32, 2-way max (free)
#define SOP  65   // so row stride

__constant__ int   kStart[7] = {0, 64, 496, 1376, 2496, 3360, 3888};
__constant__ unsigned kMagic[7] = {262144u, 87382u, 52429u, 37450u, 29128u, 23832u, 20165u}; // 2^18/d rounded up, d=2*l3+1
__constant__ int   kVpOff[7] = {0, 4, 13, 24, 34, 40, 43};
__constant__ unsigned char kVp[44] = {
  0, 5, 10, 15,                                  // l3=0
  1, 4, 5, 6, 9, 10, 11, 14, 15,                 // l3=1
  2, 5, 6, 7, 8, 9, 10, 11, 13, 14, 15,          // l3=2 ((1,3) before (2,0))
  3, 6, 7, 9, 10, 11, 12, 13, 14, 15,            // l3=3 ((2,3) before (3,0))
  7, 10, 11, 13, 14, 15,                         // l3=4
  11, 14, 15,                                    // l3=5
  15};                                           // l3=6
__constant__ int kBase[4] = {0, 4, 16, 36};  // offset of first slot of each l

__device__ __forceinline__ void decode_h(int h, int& i1, int& i2,
                                         int& n1, int& n2, int& l1l2) {
  int l3 = (h >= 64) + (h >= 496) + (h >= 1376) + (h >= 2496) + (h >= 3360) + (h >= 3888);
  unsigned hl = (unsigned)(h - kStart[l3]);
  int pair = (int)((hl * kMagic[l3]) >> 18);   // hl / (2*l3+1), exact in range
  int slot = pair & 15;
  int vp   = pair >> 4;
  l1l2 = (int)kVp[kVpOff[l3] + vp];
  int l1 = l1l2 >> 2, l2 = l1l2 & 3;
  n1 = 2 * l1 + 1;
  n2 = 2 * l2 + 1;
  i1 = kBase[l1] + (slot >> 2) * n1;
  i2 = kBase[l2] + (slot & 3) * n2;
}

// ---- prep: compact cb rows + decode metadata ----
__global__ __launch_bounds__(256) void prep_kernel(const float* __restrict__ cb,
                                                   float* __restrict__ table,
                                                   int* __restrict__ meta) {
  int idx = blockIdx.x * 256 + threadIdx.x;   // 1024 blocks -> 262144 = 4096*64
  int h = idx >> 6, e = idx & 63;
  int i1, i2, n1, n2, c;
  decode_h(h, i1, i2, n1, n2, c);
  if (e == 0) meta[h] = i1 | (i2 << 8) | (c << 16);
  unsigned mg = (n2 == 1) ? 65536u : (n2 == 3) ? 21846u : (n2 == 5) ? 13108u : 9363u;
  int qi = (int)(((unsigned)e * mg) >> 16);   // e / n2, exact for e < 64
  int rj = e - qi * n2;
  float v = 0.f;
  if (e < n1 * n2) v = cb[(size_t)h * 4096 + (i1 + qi) * 64 + (i2 + rj)];
  table[(size_t)h * 64 + e] = v;
}

template <int N1, int N2>
__device__ __forceinline__ float inner_tp(const float* __restrict__ rr,
                                          const float* __restrict__ s1r,
                                          const float* __restrict__ s2r,
                                          int i1, int i2) {
  float bb[N2], aa[N1];
#pragma unroll
  for (int j = 0; j < N2; ++j) bb[j] = s2r[i2 + j];   // adjacent -> ds_read2_b32
#pragma unroll
  for (int i = 0; i < N1; ++i) aa[i] = s1r[i1 + i];   // adjacent -> ds_read2_b32
  float acc0 = 0.f, acc1 = 0.f;
#pragma unroll
  for (int i = 0; i < N1; ++i) {
    // rr is wave-uniform with compile-time offsets -> s_load into SGPRs;
    // the fma reads the SGPR operand directly (no readlane, no VGPR copy).
    float tsum = rr[i * N2] * bb[0];
#pragma unroll
    for (int j = 1; j < N2; ++j) tsum = fmaf(rr[i * N2 + j], bb[j], tsum);
    if (i & 1) acc1 = fmaf(aa[i], tsum, acc1);
    else       acc0 = fmaf(aa[i], tsum, acc0);
  }
  return acc0 + acc1;
}

__global__ __launch_bounds__(512) void tp_kernel(
    const float* __restrict__ in1, const float* __restrict__ in2,
    const float* __restrict__ table, const int* __restrict__ meta,
    float* __restrict__ out) {
  __shared__ float s1[64 * SDIM];   // [batch][dim], stride 65
  __shared__ float s2[64 * SDIM];
  __shared__ float so[16 * SOP];    // quarter of the 64x64 output tile

  const int tid = threadIdx.x;
  const int b0 = blockIdx.x << 6;   // batch tile (64)
  const int h0 = blockIdx.y << 6;   // h tile (64)
  const int w = tid >> 6;           // wave id 0..7
  const int t = tid & 63;           // lane = batch element

  // meta for phase 0, prefetched (scalar loads, off the critical path)
  int mcur0 = meta[__builtin_amdgcn_readfirstlane(h0 + w)];
  int mcur1 = meta[__builtin_amdgcn_readfirstlane(h0 + 8 + w)];

  // ---- stage in1/in2 tiles into LDS, [batch][dim] (no transpose) ----
  const float4* g1 = reinterpret_cast<const float4*>(in1 + (size_t)b0 * 64);
  const float4* g2 = reinterpret_cast<const float4*>(in2 + (size_t)b0 * 64);
#pragma unroll
  for (int r = 0; r < 2; ++r) {
    int idx4 = r * 512 + tid;          // float4 index into 64x64 tile
    float4 v1 = g1[idx4];
    float4 v2 = g2[idx4];
    int bl = idx4 >> 4;                // batch row (16 float4 per row)
    int d0 = (idx4 & 15) << 2;         // dim start
    float* p1 = &s1[bl * SDIM + d0];
    float* p2 = &s2[bl * SDIM + d0];
    p1[0] = v1.x; p1[1] = v1.y; p1[2] = v1.z; p1[3] = v1.w;
    p2[0] = v2.x; p2[1] = v2.y; p2[2] = v2.z; p2[3] = v2.w;
  }
  __syncthreads();

  const float* s1r = &s1[t * SDIM];
  const float* s2r = &s2[t * SDIM];

#pragma unroll 1
  for (int q = 0; q < 4; ++q) {
    // prefetch next phase's meta (clamped to phase 0 on last iteration)
    int mj = (q < 3) ? (16 * (q + 1)) : 0;
    int mnxt0 = meta[__builtin_amdgcn_readfirstlane(h0 + mj + w)];
    int mnxt1 = meta[__builtin_amdgcn_readfirstlane(h0 + mj + 8 + w)];

#pragma unroll 1
    for (int m = 0; m < 2; ++m) {
      int mm = m ? mcur1 : mcur0;
      int i1 = mm & 255;
      int i2 = (mm >> 8) & 255;
      int l1l2 = (mm >> 16) & 255;
      int h = __builtin_amdgcn_readfirstlane(h0 + 16 * q + 8 * m + w);
      const float* rr = table + ((size_t)h << 6);   // wave-uniform -> s_load

      float acc = 0.f;
#define TP_CASE(L1, L2) \
      case (L1 * 4 + L2): acc = inner_tp<2 * L1 + 1, 2 * L2 + 1>(rr, s1r, s2r, i1, i2); break;
      switch (l1l2) {
        TP_CASE(0, 0) TP_CASE(0, 1) TP_CASE(0, 2) TP_CASE(0, 3)
        TP_CASE(1, 0) TP_CASE(1, 1) TP_CASE(1, 2) TP_CASE(1, 3)
        TP_CASE(2, 0) TP_CASE(2, 1) TP_CASE(2, 2) TP_CASE(2, 3)
        TP_CASE(3, 0) TP_CASE(3, 1) TP_CASE(3, 2) TP_CASE(3, 3)
        default: break;
      }
#undef TP_CASE
      so[(8 * m + w) * SOP + t] = acc;
    }
    __syncthreads();

    // ---- flush quarter: 16 h-rows x 64 batches; 256 threads x float4 ----
    if (tid < 256) {
      int bl = tid >> 2;               // batch row 0..63
      int hs = (tid & 3) << 2;         // h offset 0,4,8,12
      const float* sp = &so[hs * SOP + bl];
      float4 v;
      v.x = sp[0];
      v.y = sp[SOP];
      v.z = sp[2 * SOP];
      v.w = sp[3 * SOP];
      *reinterpret_cast<float4*>(out + (size_t)(b0 + bl) * 4096 + h0 + 16 * q + hs) = v;
    }
    if (q < 3) __syncthreads();   // so reused next phase
    mcur0 = mnxt0;
    mcur1 = mnxt1;
  }
}

extern "C" void kernel_launch(void* const* d_in, const int* in_sizes, int n_in,
                              void* d_out, int out_size, void* d_ws, size_t ws_size,
                              hipStream_t stream) {
  const float* in1 = (const float*)d_in[0];
  const float* in2 = (const float*)d_in[1];
  const float* cb  = (const float*)d_in[2];
  float* out = (float*)d_out;
  float* table = (float*)d_ws;                       // 4096*64*4 = 1 MB
  int* meta = (int*)((char*)d_ws + (size_t)4096 * 64 * 4);   // +16 KB
  (void)in_sizes; (void)n_in; (void)out_size; (void)ws_size;
  prep_kernel<<<1024, 256, 0, stream>>>(cb, table, meta);
  tp_kernel<<<dim3(64, 64), 512, 0, stream>>>(in1, in2, table, meta, out);
}

// Round 7
// 139.588 us; speedup vs baseline: 1.0705x; 1.0705x over previous
//
#include <hip/hip_runtime.h>

// out[b,h] = sum_{i,j} cb[h, i*64+j] * in1[b,i] * in2[b,j]
// B = 4096, dim1 = dim2 = 64, H = 4096.
//
// Round-6 = round-4 base (VGPR cb prefetch + readlane broadcast; the
// round-5 SGPR-direct path stalls on lgkmcnt(0) drains: s_load results
// force draining in-flight ds_reads) + row-PAIR fusion:
//   - wave w handles adjacent rows (h0+16q+2w, +1). Rows in the same
//     (combo,slot) run (~2/3 of pairs, detected by meta equality, wave-
//     uniform) share aa/bb LDS loads and one switch dispatch.
//   - so tile batch-major stride 17: pair writes -> ds_write2_b32,
//     flush reads -> ds_read2_b32.

#define SDIM 65   // s1/s2 row stride (bank-rotated, 2-way max = free)
#define SOH  17   // so row stride (h-minor)

__constant__ int   kStart[7] = {0, 64, 496, 1376, 2496, 3360, 3888};
__constant__ unsigned kMagic[7] = {262144u, 87382u, 52429u, 37450u, 29128u, 23832u, 20165u}; // 2^18/d rounded up, d=2*l3+1
__constant__ int   kVpOff[7] = {0, 4, 13, 24, 34, 40, 43};
__constant__ unsigned char kVp[44] = {
  0, 5, 10, 15,                                  // l3=0
  1, 4, 5, 6, 9, 10, 11, 14, 15,                 // l3=1
  2, 5, 6, 7, 8, 9, 10, 11, 13, 14, 15,          // l3=2 ((1,3) before (2,0))
  3, 6, 7, 9, 10, 11, 12, 13, 14, 15,            // l3=3 ((2,3) before (3,0))
  7, 10, 11, 13, 14, 15,                         // l3=4
  11, 14, 15,                                    // l3=5
  15};                                           // l3=6
__constant__ int kBase[4] = {0, 4, 16, 36};  // offset of first slot of each l

__device__ __forceinline__ void decode_h(int h, int& i1, int& i2,
                                         int& n1, int& n2, int& l1l2) {
  int l3 = (h >= 64) + (h >= 496) + (h >= 1376) + (h >= 2496) + (h >= 3360) + (h >= 3888);
  unsigned hl = (unsigned)(h - kStart[l3]);
  int pair = (int)((hl * kMagic[l3]) >> 18);   // hl / (2*l3+1), exact in range
  int slot = pair & 15;
  int vp   = pair >> 4;
  l1l2 = (int)kVp[kVpOff[l3] + vp];
  int l1 = l1l2 >> 2, l2 = l1l2 & 3;
  n1 = 2 * l1 + 1;
  n2 = 2 * l2 + 1;
  i1 = kBase[l1] + (slot >> 2) * n1;
  i2 = kBase[l2] + (slot & 3) * n2;
}

// ---- prep: compact cb rows + decode metadata ----
__global__ __launch_bounds__(256) void prep_kernel(const float* __restrict__ cb,
                                                   float* __restrict__ table,
                                                   int* __restrict__ meta) {
  int idx = blockIdx.x * 256 + threadIdx.x;   // 1024 blocks -> 262144 = 4096*64
  int h = idx >> 6, e = idx & 63;
  int i1, i2, n1, n2, c;
  decode_h(h, i1, i2, n1, n2, c);
  if (e == 0) meta[h] = i1 | (i2 << 8) | (c << 16);
  unsigned mg = (n2 == 1) ? 65536u : (n2 == 3) ? 21846u : (n2 == 5) ? 13108u : 9363u;
  int qi = (int)(((unsigned)e * mg) >> 16);   // e / n2, exact for e < 64
  int rj = e - qi * n2;
  float v = 0.f;
  if (e < n1 * n2) v = cb[(size_t)h * 4096 + (i1 + qi) * 64 + (i2 + rj)];
  table[(size_t)h * 64 + e] = v;
}

__device__ __forceinline__ float lane_bcast(float v, int l) {
  union { float f; int i; } u;
  u.f = v;
  u.i = __builtin_amdgcn_readlane(u.i, l);
  return u.f;
}

// single row
template <int N1, int N2>
__device__ __forceinline__ float inner_tp(float vrow,
                                          const float* __restrict__ s1r,
                                          const float* __restrict__ s2r,
                                          int i1, int i2) {
  float bb[N2], aa[N1];
#pragma unroll
  for (int j = 0; j < N2; ++j) bb[j] = s2r[i2 + j];   // ds_read2_b32
#pragma unroll
  for (int i = 0; i < N1; ++i) aa[i] = s1r[i1 + i];
  float acc0 = 0.f, acc1 = 0.f;
#pragma unroll
  for (int i = 0; i < N1; ++i) {
    float tsum = lane_bcast(vrow, i * N2) * bb[0];
#pragma unroll
    for (int j = 1; j < N2; ++j) tsum = fmaf(lane_bcast(vrow, i * N2 + j), bb[j], tsum);
    if (i & 1) acc1 = fmaf(aa[i], tsum, acc1);
    else       acc0 = fmaf(aa[i], tsum, acc0);
  }
  return acc0 + acc1;
}

// fused same-run pair: aa/bb loaded once for both rows
template <int N1, int N2>
__device__ __forceinline__ void inner_tp2(float v0, float v1,
                                          const float* __restrict__ s1r,
                                          const float* __restrict__ s2r,
                                          int i1, int i2,
                                          float& o0, float& o1) {
  float bb[N2], aa[N1];
#pragma unroll
  for (int j = 0; j < N2; ++j) bb[j] = s2r[i2 + j];
#pragma unroll
  for (int i = 0; i < N1; ++i) aa[i] = s1r[i1 + i];
  float a0 = 0.f, a1 = 0.f, b0 = 0.f, b1 = 0.f;
#pragma unroll
  for (int i = 0; i < N1; ++i) {
    float t0 = lane_bcast(v0, i * N2) * bb[0];
    float t1 = lane_bcast(v1, i * N2) * bb[0];
#pragma unroll
    for (int j = 1; j < N2; ++j) {
      t0 = fmaf(lane_bcast(v0, i * N2 + j), bb[j], t0);
      t1 = fmaf(lane_bcast(v1, i * N2 + j), bb[j], t1);
    }
    if (i & 1) { a1 = fmaf(aa[i], t0, a1); b1 = fmaf(aa[i], t1, b1); }
    else       { a0 = fmaf(aa[i], t0, a0); b0 = fmaf(aa[i], t1, b0); }
  }
  o0 = a0 + a1;
  o1 = b0 + b1;
}

__global__ __launch_bounds__(512) void tp_kernel(
    const float* __restrict__ in1, const float* __restrict__ in2,
    const float* __restrict__ table, const int* __restrict__ meta,
    float* __restrict__ out) {
  __shared__ float s1[64 * SDIM];   // [batch][dim], stride 65
  __shared__ float s2[64 * SDIM];
  __shared__ float so[64 * SOH];    // [batch][local_h], stride 17 (quarter)

  const int tid = threadIdx.x;
  const int b0 = blockIdx.x << 6;   // batch tile (64)
  const int h0 = blockIdx.y << 6;   // h tile (64)
  const int w = tid >> 6;           // wave id 0..7: rows (16q+2w, +1)
  const int t = tid & 63;           // lane = batch element

  // wave's cb-table rows; lane t holds entry t. Pair rows of quarter q at
  // tb[q<<10] and tb[(q<<10)+64]. Prefetch phase 0 now (hidden by staging).
  const float* tb = table + ((size_t)(h0 + 2 * w) << 6) + t;
  float cur0 = tb[0];
  float cur1 = tb[64];
  const int2* meta2 = reinterpret_cast<const int2*>(meta);
  int2 mcur = meta2[__builtin_amdgcn_readfirstlane((h0 >> 1) + w)];

  // ---- stage in1/in2 tiles into LDS, [batch][dim] ----
  const float4* g1 = reinterpret_cast<const float4*>(in1 + (size_t)b0 * 64);
  const float4* g2 = reinterpret_cast<const float4*>(in2 + (size_t)b0 * 64);
#pragma unroll
  for (int r = 0; r < 2; ++r) {
    int idx4 = r * 512 + tid;          // float4 index into 64x64 tile
    float4 v1 = g1[idx4];
    float4 v2 = g2[idx4];
    int bl = idx4 >> 4;                // batch row (16 float4 per row)
    int d0 = (idx4 & 15) << 2;         // dim start
    float* p1 = &s1[bl * SDIM + d0];
    float* p2 = &s2[bl * SDIM + d0];
    p1[0] = v1.x; p1[1] = v1.y; p1[2] = v1.z; p1[3] = v1.w;
    p2[0] = v2.x; p2[1] = v2.y; p2[2] = v2.z; p2[3] = v2.w;
  }
  __syncthreads();

  const float* s1r = &s1[t * SDIM];
  const float* s2r = &s2[t * SDIM];

#pragma unroll 1
  for (int q = 0; q < 4; ++q) {
    // prefetch next quarter's pair + meta (clamped on last iteration)
    int qn = (q < 3) ? (q + 1) : 0;
    float nxt0 = tb[qn << 10];
    float nxt1 = tb[(qn << 10) + 64];
    int2 mnxt = meta2[__builtin_amdgcn_readfirstlane((h0 >> 1) + 8 * qn + w)];

    int mm0 = mcur.x, mm1 = mcur.y;
    float r0 = 0.f, r1 = 0.f;
    if (mm0 == mm1) {
      // same (combo, slot) run: share aa/bb, one dispatch
      int i1 = mm0 & 255, i2 = (mm0 >> 8) & 255;
#define TP2_CASE(L1, L2) \
      case (L1 * 4 + L2): inner_tp2<2 * L1 + 1, 2 * L2 + 1>(cur0, cur1, s1r, s2r, i1, i2, r0, r1); break;
      switch (mm0 >> 16) {
        TP2_CASE(0, 0) TP2_CASE(0, 1) TP2_CASE(0, 2) TP2_CASE(0, 3)
        TP2_CASE(1, 0) TP2_CASE(1, 1) TP2_CASE(1, 2) TP2_CASE(1, 3)
        TP2_CASE(2, 0) TP2_CASE(2, 1) TP2_CASE(2, 2) TP2_CASE(2, 3)
        TP2_CASE(3, 0) TP2_CASE(3, 1) TP2_CASE(3, 2) TP2_CASE(3, 3)
        default: break;
      }
#undef TP2_CASE
    } else {
#define TP_CASE(L1, L2, VR, DST, MI1, MI2) \
      case (L1 * 4 + L2): DST = inner_tp<2 * L1 + 1, 2 * L2 + 1>(VR, s1r, s2r, MI1, MI2); break;
      {
        int i1 = mm0 & 255, i2 = (mm0 >> 8) & 255;
        switch (mm0 >> 16) {
          TP_CASE(0, 0, cur0, r0, i1, i2) TP_CASE(0, 1, cur0, r0, i1, i2)
          TP_CASE(0, 2, cur0, r0, i1, i2) TP_CASE(0, 3, cur0, r0, i1, i2)
          TP_CASE(1, 0, cur0, r0, i1, i2) TP_CASE(1, 1, cur0, r0, i1, i2)
          TP_CASE(1, 2, cur0, r0, i1, i2) TP_CASE(1, 3, cur0, r0, i1, i2)
          TP_CASE(2, 0, cur0, r0, i1, i2) TP_CASE(2, 1, cur0, r0, i1, i2)
          TP_CASE(2, 2, cur0, r0, i1, i2) TP_CASE(2, 3, cur0, r0, i1, i2)
          TP_CASE(3, 0, cur0, r0, i1, i2) TP_CASE(3, 1, cur0, r0, i1, i2)
          TP_CASE(3, 2, cur0, r0, i1, i2) TP_CASE(3, 3, cur0, r0, i1, i2)
          default: break;
        }
      }
      {
        int i1 = mm1 & 255, i2 = (mm1 >> 8) & 255;
        switch (mm1 >> 16) {
          TP_CASE(0, 0, cur1, r1, i1, i2) TP_CASE(0, 1, cur1, r1, i1, i2)
          TP_CASE(0, 2, cur1, r1, i1, i2) TP_CASE(0, 3, cur1, r1, i1, i2)
          TP_CASE(1, 0, cur1, r1, i1, i2) TP_CASE(1, 1, cur1, r1, i1, i2)
          TP_CASE(1, 2, cur1, r1, i1, i2) TP_CASE(1, 3, cur1, r1, i1, i2)
          TP_CASE(2, 0, cur1, r1, i1, i2) TP_CASE(2, 1, cur1, r1, i1, i2)
          TP_CASE(2, 2, cur1, r1, i1, i2) TP_CASE(2, 3, cur1, r1, i1, i2)
          TP_CASE(3, 0, cur1, r1, i1, i2) TP_CASE(3, 1, cur1, r1, i1, i2)
          TP_CASE(3, 2, cur1, r1, i1, i2) TP_CASE(3, 3, cur1, r1, i1, i2)
          default: break;
        }
      }
#undef TP_CASE
    }
    // so[batch][local_h]: adjacent pair -> ds_write2_b32
    float* sw = &so[t * SOH + 2 * w];
    sw[0] = r0;
    sw[1] = r1;
    __syncthreads();

    // ---- flush quarter: 16 h x 64 b; 256 threads x float4 ----
    if (tid < 256) {
      int bl = tid >> 2;               // batch row 0..63
      int hs = (tid & 3) << 2;         // h offset 0,4,8,12
      const float* sp = &so[bl * SOH + hs];
      float4 v;
      v.x = sp[0]; v.y = sp[1]; v.z = sp[2]; v.w = sp[3];   // 2x ds_read2
      *reinterpret_cast<float4*>(out + (size_t)(b0 + bl) * 4096 + h0 + 16 * q + hs) = v;
    }
    if (q < 3) __syncthreads();   // so reused next quarter
    cur0 = nxt0; cur1 = nxt1;
    mcur = mnxt;
  }
}

extern "C" void kernel_launch(void* const* d_in, const int* in_sizes, int n_in,
                              void* d_out, int out_size, void* d_ws, size_t ws_size,
                              hipStream_t stream) {
  const float* in1 = (const float*)d_in[0];
  const float* in2 = (const float*)d_in[1];
  const float* cb  = (const float*)d_in[2];
  float* out = (float*)d_out;
  float* table = (float*)d_ws;                       // 4096*64*4 = 1 MB
  int* meta = (int*)((char*)d_ws + (size_t)4096 * 64 * 4);   // +16 KB
  (void)in_sizes; (void)n_in; (void)out_size; (void)ws_size;
  prep_kernel<<<1024, 256, 0, stream>>>(cb, table, meta);
  tp_kernel<<<dim3(64, 64), 512, 0, stream>>>(in1, in2, table, meta, out);
}

// Round 8
// 139.057 us; speedup vs baseline: 1.0746x; 1.0038x over previous
//
#include <hip/hip_runtime.h>

// out[b,h] = sum_{i,j} cb[h, i*64+j] * in1[b,i] * in2[b,j]
// B = 4096, dim1 = dim2 = 64, H = 4096.
//
// Round-7 = round-6 (pair fusion, VGPR cb prefetch, readlane broadcast)
// + float2 BATCH PACKING: lane t handles batches (2t, 2t+1); blocks cover
// 128b x 64h. One readlane feeds two fmas; aa/bb LDS reads are b64,
// halving per-batch LDS-pipe and VALU pressure. LDS 75 KB -> 2 blocks/CU.

typedef float vf2 __attribute__((ext_vector_type(2)));

#define SDIM 65   // s1v/s2v row stride in float2 units
#define SOH  17   // so row stride (h-minor, odd -> 2-way banks on writes)

__constant__ int   kStart[7] = {0, 64, 496, 1376, 2496, 3360, 3888};
__constant__ unsigned kMagic[7] = {262144u, 87382u, 52429u, 37450u, 29128u, 23832u, 20165u}; // 2^18/d rounded up, d=2*l3+1
__constant__ int   kVpOff[7] = {0, 4, 13, 24, 34, 40, 43};
__constant__ unsigned char kVp[44] = {
  0, 5, 10, 15,                                  // l3=0
  1, 4, 5, 6, 9, 10, 11, 14, 15,                 // l3=1
  2, 5, 6, 7, 8, 9, 10, 11, 13, 14, 15,          // l3=2 ((1,3) before (2,0))
  3, 6, 7, 9, 10, 11, 12, 13, 14, 15,            // l3=3 ((2,3) before (3,0))
  7, 10, 11, 13, 14, 15,                         // l3=4
  11, 14, 15,                                    // l3=5
  15};                                           // l3=6
__constant__ int kBase[4] = {0, 4, 16, 36};  // offset of first slot of each l

__device__ __forceinline__ void decode_h(int h, int& i1, int& i2,
                                         int& n1, int& n2, int& l1l2) {
  int l3 = (h >= 64) + (h >= 496) + (h >= 1376) + (h >= 2496) + (h >= 3360) + (h >= 3888);
  unsigned hl = (unsigned)(h - kStart[l3]);
  int pair = (int)((hl * kMagic[l3]) >> 18);   // hl / (2*l3+1), exact in range
  int slot = pair & 15;
  int vp   = pair >> 4;
  l1l2 = (int)kVp[kVpOff[l3] + vp];
  int l1 = l1l2 >> 2, l2 = l1l2 & 3;
  n1 = 2 * l1 + 1;
  n2 = 2 * l2 + 1;
  i1 = kBase[l1] + (slot >> 2) * n1;
  i2 = kBase[l2] + (slot & 3) * n2;
}

// ---- prep: compact cb rows + decode metadata ----
__global__ __launch_bounds__(256) void prep_kernel(const float* __restrict__ cb,
                                                   float* __restrict__ table,
                                                   int* __restrict__ meta) {
  int idx = blockIdx.x * 256 + threadIdx.x;   // 1024 blocks -> 262144 = 4096*64
  int h = idx >> 6, e = idx & 63;
  int i1, i2, n1, n2, c;
  decode_h(h, i1, i2, n1, n2, c);
  if (e == 0) meta[h] = i1 | (i2 << 8) | (c << 16);
  unsigned mg = (n2 == 1) ? 65536u : (n2 == 3) ? 21846u : (n2 == 5) ? 13108u : 9363u;
  int qi = (int)(((unsigned)e * mg) >> 16);   // e / n2, exact for e < 64
  int rj = e - qi * n2;
  float v = 0.f;
  if (e < n1 * n2) v = cb[(size_t)h * 4096 + (i1 + qi) * 64 + (i2 + rj)];
  table[(size_t)h * 64 + e] = v;
}

__device__ __forceinline__ float lane_bcast(float v, int l) {
  union { float f; int i; } u;
  u.f = v;
  u.i = __builtin_amdgcn_readlane(u.i, l);
  return u.f;
}

__device__ __forceinline__ vf2 splat(float c) { vf2 r; r.x = c; r.y = c; return r; }

// single row, 2 batches packed
template <int N1, int N2>
__device__ __forceinline__ vf2 inner_tp(float vrow,
                                        const vf2* __restrict__ s1r,
                                        const vf2* __restrict__ s2r,
                                        int i1, int i2) {
  vf2 bb[N2], aa[N1];
#pragma unroll
  for (int j = 0; j < N2; ++j) bb[j] = s2r[i2 + j];   // ds_read2_b64
#pragma unroll
  for (int i = 0; i < N1; ++i) aa[i] = s1r[i1 + i];
  vf2 acc0 = splat(0.f), acc1 = splat(0.f);
#pragma unroll
  for (int i = 0; i < N1; ++i) {
    vf2 t = splat(lane_bcast(vrow, i * N2)) * bb[0];
#pragma unroll
    for (int j = 1; j < N2; ++j)
      t = __builtin_elementwise_fma(splat(lane_bcast(vrow, i * N2 + j)), bb[j], t);
    if (i & 1) acc1 = __builtin_elementwise_fma(aa[i], t, acc1);
    else       acc0 = __builtin_elementwise_fma(aa[i], t, acc0);
  }
  return acc0 + acc1;
}

// fused same-run pair x 2 batches: aa/bb loaded once for both rows
template <int N1, int N2>
__device__ __forceinline__ void inner_tp2(float v0, float v1,
                                          const vf2* __restrict__ s1r,
                                          const vf2* __restrict__ s2r,
                                          int i1, int i2,
                                          vf2& o0, vf2& o1) {
  vf2 bb[N2], aa[N1];
#pragma unroll
  for (int j = 0; j < N2; ++j) bb[j] = s2r[i2 + j];
#pragma unroll
  for (int i = 0; i < N1; ++i) aa[i] = s1r[i1 + i];
  vf2 a0 = splat(0.f), a1 = splat(0.f), b0 = splat(0.f), b1 = splat(0.f);
#pragma unroll
  for (int i = 0; i < N1; ++i) {
    vf2 t0 = splat(lane_bcast(v0, i * N2)) * bb[0];
    vf2 t1 = splat(lane_bcast(v1, i * N2)) * bb[0];
#pragma unroll
    for (int j = 1; j < N2; ++j) {
      t0 = __builtin_elementwise_fma(splat(lane_bcast(v0, i * N2 + j)), bb[j], t0);
      t1 = __builtin_elementwise_fma(splat(lane_bcast(v1, i * N2 + j)), bb[j], t1);
    }
    if (i & 1) { a1 = __builtin_elementwise_fma(aa[i], t0, a1);
                 b1 = __builtin_elementwise_fma(aa[i], t1, b1); }
    else       { a0 = __builtin_elementwise_fma(aa[i], t0, a0);
                 b0 = __builtin_elementwise_fma(aa[i], t1, b0); }
  }
  o0 = a0 + a1;
  o1 = b0 + b1;
}

__global__ __launch_bounds__(512) void tp_kernel(
    const float* __restrict__ in1, const float* __restrict__ in2,
    const float* __restrict__ table, const int* __restrict__ meta,
    float* __restrict__ out) {
  __shared__ vf2 s1v[64 * SDIM];    // [batch_pair][dim], float2 = (b2t, b2t+1)
  __shared__ vf2 s2v[64 * SDIM];
  __shared__ float so[128 * SOH];   // [batch][local_h] quarter tile

  const int tid = threadIdx.x;
  const int b0 = blockIdx.x << 7;   // batch tile (128)
  const int h0 = blockIdx.y << 6;   // h tile (64)
  const int w = tid >> 6;           // wave id 0..7: rows (16q+2w, +1)
  const int t = tid & 63;           // lane = batch PAIR (2t, 2t+1)

  // wave's cb-table rows; lane t holds entry t. Prefetch quarter 0 now.
  const float* tb = table + ((size_t)(h0 + 2 * w) << 6) + t;
  float cur0 = tb[0];
  float cur1 = tb[64];
  const int2* meta2 = reinterpret_cast<const int2*>(meta);
  int2 mcur = meta2[__builtin_amdgcn_readfirstlane((h0 >> 1) + w)];

  // ---- stage in1/in2 tiles, interleaving batch pairs into float2 ----
#pragma unroll
  for (int it = 0; it < 2; ++it) {
    int task = it * 512 + tid;         // 1024 tasks = 64 pairs x 16 float4
    int bp = task >> 4;                // batch pair 0..63
    int d4 = (task & 15) << 2;         // dim start
    const float* r0p = in1 + (size_t)(b0 + 2 * bp) * 64 + d4;
    const float* r1p = r0p + 64;
    float4 a0 = *reinterpret_cast<const float4*>(r0p);
    float4 a1 = *reinterpret_cast<const float4*>(r1p);
    vf2* p = &s1v[bp * SDIM + d4];
    vf2 u;
    u.x = a0.x; u.y = a1.x; p[0] = u;
    u.x = a0.y; u.y = a1.y; p[1] = u;
    u.x = a0.z; u.y = a1.z; p[2] = u;
    u.x = a0.w; u.y = a1.w; p[3] = u;
    const float* q0p = in2 + (size_t)(b0 + 2 * bp) * 64 + d4;
    const float* q1p = q0p + 64;
    float4 c0 = *reinterpret_cast<const float4*>(q0p);
    float4 c1 = *reinterpret_cast<const float4*>(q1p);
    vf2* p2 = &s2v[bp * SDIM + d4];
    u.x = c0.x; u.y = c1.x; p2[0] = u;
    u.x = c0.y; u.y = c1.y; p2[1] = u;
    u.x = c0.z; u.y = c1.z; p2[2] = u;
    u.x = c0.w; u.y = c1.w; p2[3] = u;
  }
  __syncthreads();

  const vf2* s1r = &s1v[t * SDIM];
  const vf2* s2r = &s2v[t * SDIM];

#pragma unroll 1
  for (int q = 0; q < 4; ++q) {
    // prefetch next quarter's cb pair + meta (clamped on last iteration)
    int qn = (q < 3) ? (q + 1) : 0;
    float nxt0 = tb[qn << 10];
    float nxt1 = tb[(qn << 10) + 64];
    int2 mnxt = meta2[__builtin_amdgcn_readfirstlane((h0 >> 1) + 8 * qn + w)];

    int mm0 = mcur.x, mm1 = mcur.y;
    vf2 r0 = splat(0.f), r1 = splat(0.f);
    if (mm0 == mm1) {
      int i1 = mm0 & 255, i2 = (mm0 >> 8) & 255;
#define TP2_CASE(L1, L2) \
      case (L1 * 4 + L2): inner_tp2<2 * L1 + 1, 2 * L2 + 1>(cur0, cur1, s1r, s2r, i1, i2, r0, r1); break;
      switch (mm0 >> 16) {
        TP2_CASE(0, 0) TP2_CASE(0, 1) TP2_CASE(0, 2) TP2_CASE(0, 3)
        TP2_CASE(1, 0) TP2_CASE(1, 1) TP2_CASE(1, 2) TP2_CASE(1, 3)
        TP2_CASE(2, 0) TP2_CASE(2, 1) TP2_CASE(2, 2) TP2_CASE(2, 3)
        TP2_CASE(3, 0) TP2_CASE(3, 1) TP2_CASE(3, 2) TP2_CASE(3, 3)
        default: break;
      }
#undef TP2_CASE
    } else {
#define TP_CASE(L1, L2, VR, DST, MI1, MI2) \
      case (L1 * 4 + L2): DST = inner_tp<2 * L1 + 1, 2 * L2 + 1>(VR, s1r, s2r, MI1, MI2); break;
      {
        int i1 = mm0 & 255, i2 = (mm0 >> 8) & 255;
        switch (mm0 >> 16) {
          TP_CASE(0, 0, cur0, r0, i1, i2) TP_CASE(0, 1, cur0, r0, i1, i2)
          TP_CASE(0, 2, cur0, r0, i1, i2) TP_CASE(0, 3, cur0, r0, i1, i2)
          TP_CASE(1, 0, cur0, r0, i1, i2) TP_CASE(1, 1, cur0, r0, i1, i2)
          TP_CASE(1, 2, cur0, r0, i1, i2) TP_CASE(1, 3, cur0, r0, i1, i2)
          TP_CASE(2, 0, cur0, r0, i1, i2) TP_CASE(2, 1, cur0, r0, i1, i2)
          TP_CASE(2, 2, cur0, r0, i1, i2) TP_CASE(2, 3, cur0, r0, i1, i2)
          TP_CASE(3, 0, cur0, r0, i1, i2) TP_CASE(3, 1, cur0, r0, i1, i2)
          TP_CASE(3, 2, cur0, r0, i1, i2) TP_CASE(3, 3, cur0, r0, i1, i2)
          default: break;
        }
      }
      {
        int i1 = mm1 & 255, i2 = (mm1 >> 8) & 255;
        switch (mm1 >> 16) {
          TP_CASE(0, 0, cur1, r1, i1, i2) TP_CASE(0, 1, cur1, r1, i1, i2)
          TP_CASE(0, 2, cur1, r1, i1, i2) TP_CASE(0, 3, cur1, r1, i1, i2)
          TP_CASE(1, 0, cur1, r1, i1, i2) TP_CASE(1, 1, cur1, r1, i1, i2)
          TP_CASE(1, 2, cur1, r1, i1, i2) TP_CASE(1, 3, cur1, r1, i1, i2)
          TP_CASE(2, 0, cur1, r1, i1, i2) TP_CASE(2, 1, cur1, r1, i1, i2)
          TP_CASE(2, 2, cur1, r1, i1, i2) TP_CASE(2, 3, cur1, r1, i1, i2)
          TP_CASE(3, 0, cur1, r1, i1, i2) TP_CASE(3, 1, cur1, r1, i1, i2)
          TP_CASE(3, 2, cur1, r1, i1, i2) TP_CASE(3, 3, cur1, r1, i1, i2)
          default: break;
        }
      }
#undef TP_CASE
    }
    // so[batch][local_h]: r0 = row h_a {b2t, b2t+1}, r1 = row h_b
    {
      float* sa = &so[(2 * t) * SOH + 2 * w];
      sa[0] = r0.x; sa[1] = r1.x;
      float* sb = &so[(2 * t + 1) * SOH + 2 * w];
      sb[0] = r0.y; sb[1] = r1.y;
    }
    __syncthreads();

    // ---- flush quarter: 16 h x 128 b; 512 threads x float4 ----
    {
      int b = tid >> 2;                // batch row 0..127
      int hs = (tid & 3) << 2;         // h offset 0,4,8,12
      const float* sp = &so[b * SOH + hs];
      float4 v;
      v.x = sp[0]; v.y = sp[1]; v.z = sp[2]; v.w = sp[3];
      *reinterpret_cast<float4*>(out + (size_t)(b0 + b) * 4096 + h0 + 16 * q + hs) = v;
    }
    if (q < 3) __syncthreads();   // so reused next quarter
    cur0 = nxt0; cur1 = nxt1;
    mcur = mnxt;
  }
}

extern "C" void kernel_launch(void* const* d_in, const int* in_sizes, int n_in,
                              void* d_out, int out_size, void* d_ws, size_t ws_size,
                              hipStream_t stream) {
  const float* in1 = (const float*)d_in[0];
  const float* in2 = (const float*)d_in[1];
  const float* cb  = (const float*)d_in[2];
  float* out = (float*)d_out;
  float* table = (float*)d_ws;                       // 4096*64*4 = 1 MB
  int* meta = (int*)((char*)d_ws + (size_t)4096 * 64 * 4);   // +16 KB
  (void)in_sizes; (void)n_in; (void)out_size; (void)ws_size;
  prep_kernel<<<1024, 256, 0, stream>>>(cb, table, meta);
  tp_kernel<<<dim3(32, 64), 512, 0, stream>>>(in1, in2, table, meta, out);
}